// Round 10
// baseline (369.993 us; speedup 1.0000x reference)
//
#include <hip/hip_runtime.h>

#define LL 128
#define STR 135            // ≡7 (mod 32); row-contiguous streams, groups 2-way-free
#define NT 1024
#define WSW 16

__device__ __forceinline__ float softplus_f(float x) { return log1pf(__expf(x)); }

// LDS-visibility-only barrier (no vmcnt drain).
__device__ __forceinline__ void lds_barrier() {
    asm volatile("s_waitcnt lgkmcnt(0)" ::: "memory");
    __builtin_amdgcn_s_barrier();
    asm volatile("" ::: "memory");
}

// LDS slabs, each 128 x STR floats:
//   AL[r][c], c>=r : A[r][c]  (incl diag);  c<r : A[c][r]  (transposed mirror)
//   SB[r][c], c>=r : S[r][c] during inside, overwritten with SL = S - log G at
//                    the cell's outside phase; c<r : mirror. Diag S = 0.
// Outside pass is pure GATHER (no RMW): child (r,c) sums
//   left-parents  (r,J): exp(A[r,c] + A[c+1,J] - SL[r,J])   (J-contiguous)
//   right-parents (I,c): exp(A[I,r-1] + A[r,c] - SL[I,c])   (I-contiguous)
extern "C" __global__ __launch_bounds__(NT, 1) void cky_kernel(
    const float* __restrict__ scores,
    const int* __restrict__ seq_lens,
    float* __restrict__ Z_out,
    float* __restrict__ marg_out)
{
    extern __shared__ float smem[];
    float* ALs = smem;
    float* SBs = smem + LL * STR;

    const int b   = blockIdx.x;
    const int tid = threadIdx.x;
    const float* s = scores + (size_t)b * LL * LL;
    float* marg = marg_out + (size_t)b * LL * LL;
    const int len = seq_lens[b];

    if (tid < LL) {
        const float sp = softplus_f(s[tid * LL + tid]);
        ALs[tid * STR + tid] = sp;     // A[i][i]
        SBs[tid * STR + tid] = 0.f;    // S[i][i] = 0
    }
    lds_barrier();

    // ================= INSIDE =================
    for (int w = 1; w < len; ++w) {
        const int cells = len - w;
        if (w < WSW) {                                   // lane-per-cell
            if (tid < cells) {
                const int i = tid, j = i + w;
                const float sv = s[i * LL + j];          // prefetched, no drain
                const float M  = ALs[i * STR + j - 1];
                const float* pL = ALs + i * STR + i;     // A[i][i+e]
                const float* pR = ALs + j * STR + i + 1; // A[i+e+1][j] (mirror row)
                float acc = 0.f;
                #pragma unroll 4
                for (int e = 0; e < w; ++e)
                    acc += __expf(pL[e] + pR[e] - M);    // adjacent loads merge
                const float S = M + __logf(acc);         // acc >= exp(A[j][j]) > 0
                const float A = S + softplus_f(sv);
                ALs[i * STR + j] = A;  ALs[j * STR + i] = A;
                SBs[i * STR + j] = S;  SBs[j * STR + i] = S;
            }
        } else {                                         // g lanes per cell
            const int clw = 32 - __clz(w - 1);
            const int clc = (cells > 1) ? (32 - __clz(cells - 1)) : 0;
            int gsh = clw - 2;
            const int cap = 10 - clc; if (gsh > cap) gsh = cap;
            if (gsh > 6) gsh = 6; if (gsh < 0) gsh = 0;
            const int g = 1 << gsh;
            const int gid = tid >> gsh, v = tid & (g - 1);
            if (gid < cells) {
                const int i = gid, j = i + w;
                const float sv = s[i * LL + j];
                const float M  = ALs[i * STR + j - 1];
                const float* pL = ALs + i * STR + i;
                const float* pR = ALs + j * STR + i + 1;
                float acc = 0.f;
                const int e0 = 2 * v;
                for (int t = 0; 2 * g * t < w; ++t) {    // wave-uniform-ish guard
                    const int e = e0 + 2 * g * t;
                    float l0 = pL[e], l1 = pL[e + 1];    // speculative; masked below
                    float r0 = pR[e], r1 = pR[e + 1];
                    float x0 = __expf(l0 + r0 - M);
                    float x1 = __expf(l1 + r1 - M);
                    acc += (e     < w) ? x0 : 0.f;
                    acc += (e + 1 < w) ? x1 : 0.f;
                }
                for (int off = g >> 1; off; off >>= 1) acc += __shfl_xor(acc, off, 64);
                if (v == 0) {
                    const float S = M + __logf(acc);
                    const float A = S + softplus_f(sv);
                    ALs[i * STR + j] = A;  ALs[j * STR + i] = A;
                    SBs[i * STR + j] = S;  SBs[j * STR + i] = S;
                }
            }
        }
        lds_barrier();
    }

    if (tid == 0) Z_out[b] = ALs[len - 1];               // A[0][len-1]

    // ================= OUTSIDE (gather, no RMW) =================
    for (int w = len - 1; w >= 0; --w) {
        const int cells = len - w;
        const int P = len - 1 - w;                       // parents per cell
        if (P < WSW) {                                   // lane-per-cell
            if (tid < cells) {
                const int r = tid, c = r + w;
                const float Aown = ALs[r * STR + c];
                float acc = 0.f;
                for (int J = c + 1; J < len; ++J)
                    acc += __expf(Aown + ALs[(c + 1) * STR + J] - SBs[r * STR + J]);
                for (int I = 0; I < r; ++I)
                    acc += __expf(ALs[(r - 1) * STR + I] + Aown - SBs[c * STR + I]);
                if (r == 0 && w == len - 1) acc += 1.f;  // root seed
                const float SL = SBs[r * STR + c] - __logf(acc);
                SBs[r * STR + c] = SL;  SBs[c * STR + r] = SL;
            }
        } else {                                         // g lanes per cell
            const int clp = 32 - __clz(P - 1);
            const int clc = (cells > 1) ? (32 - __clz(cells - 1)) : 0;
            int gsh = clp - 2;
            const int cap = 10 - clc; if (gsh > cap) gsh = cap;
            if (gsh > 6) gsh = 6; if (gsh < 0) gsh = 0;
            const int g = 1 << gsh;
            const int gid = tid >> gsh, v = tid & (g - 1);
            if (gid < cells) {
                const int r = gid, c = r + w;
                const float Aown = ALs[r * STR + c];
                float acc = 0.f;
                // left-parents: J in (c, len)
                const int nL = len - 1 - c;
                const float* pA = ALs + (c + 1) * STR;   // A[c+1][J]
                const float* pS = SBs + r * STR;         // SL[r][J]
                const int j0 = c + 1 + 2 * v;
                for (int t = 0; 2 * g * t < nL; ++t) {
                    const int J = j0 + 2 * g * t;
                    float a0 = pA[J], a1 = pA[J + 1];    // speculative; masked
                    float s0 = pS[J], s1 = pS[J + 1];
                    float x0 = __expf(Aown + a0 - s0);
                    float x1 = __expf(Aown + a1 - s1);
                    acc += (J     < len) ? x0 : 0.f;
                    acc += (J + 1 < len) ? x1 : 0.f;
                }
                // right-parents: I in [0, r)
                const float* qA = ALs + (r - 1) * STR;   // A[I][r-1] via mirror row
                const float* qS = SBs + c * STR;         // SL[I][c] via mirror row
                const int i0 = 2 * v;
                for (int t = 0; 2 * g * t < r; ++t) {
                    const int I = i0 + 2 * g * t;
                    float a0 = qA[I], a1 = qA[I + 1];
                    float s0 = qS[I], s1 = qS[I + 1];
                    float x0 = __expf(a0 + Aown - s0);
                    float x1 = __expf(a1 + Aown - s1);
                    acc += (I     < r) ? x0 : 0.f;
                    acc += (I + 1 < r) ? x1 : 0.f;
                }
                for (int off = g >> 1; off; off >>= 1) acc += __shfl_xor(acc, off, 64);
                if (v == 0) {
                    const float SL = SBs[r * STR + c] - __logf(acc);
                    SBs[r * STR + c] = SL;  SBs[c * STR + r] = SL;
                }
            }
        }
        lds_barrier();
    }

    // ================= epilogue: marg = G * sigmoid(s), coalesced ============
    for (int idx = tid; idx < LL * LL; idx += NT) {
        const int r = idx >> 7, c = idx & (LL - 1);
        float m = 0.f;
        if (c >= r && c < len) {
            const float sp = softplus_f(s[idx]);
            const float G  = __expf(ALs[r * STR + c] - sp - SBs[r * STR + c]);
            m = G * (1.f - __expf(-sp));                 // sigmoid = 1 - e^{-softplus}
        }
        marg[idx] = m;
    }
}

extern "C" void kernel_launch(void* const* d_in, const int* in_sizes, int n_in,
                              void* d_out, int out_size, void* d_ws, size_t ws_size,
                              hipStream_t stream) {
    const float* scores  = (const float*)d_in[0];
    const int* seq_lens  = (const int*)d_in[1];
    const int B = in_sizes[1];              // 32
    float* out = (float*)d_out;
    float* Z_out = out;                     // B floats
    float* marg  = out + B;                 // B*L*L floats

    const size_t lds_bytes = (size_t)2 * LL * STR * sizeof(float);  // 138240 B
    hipFuncSetAttribute((const void*)cky_kernel,
                        hipFuncAttributeMaxDynamicSharedMemorySize,
                        (int)lds_bytes);
    cky_kernel<<<B, NT, lds_bytes, stream>>>(scores, seq_lens, Z_out, marg);
}

// Round 11
// 320.490 us; speedup vs baseline: 1.1545x; 1.1545x over previous
//
#include <hip/hip_runtime.h>

#define LL 128
#define STR 135            // ≡7 (mod 32): row and stride-STR LDS streams <=2-way (free)
#define STR1 136           // STR+1
#define NT 512
#define LARGENEG -1.0e30f

__device__ __forceinline__ float softplus_f(float x) { return log1pf(__expf(x)); }

// LDS-visibility-only barrier: waits LDS ops, leaves global loads in flight.
__device__ __forceinline__ void lds_barrier() {
    asm volatile("s_waitcnt lgkmcnt(0)" ::: "memory");
    __builtin_amdgcn_s_barrier();
    asm volatile("" ::: "memory");
}

// LDS layout:
//   Al[r*STR+c], c>=r : A[r][c]    (inside values incl. diagonal)
//   Al[r*STR+c], c< r : S[c][r]    (pre-softplus LSE, transposed; width>=1)
//   Gl[r*STR+c], c> r : left-acc  for child (r,c)          [unique writer/phase]
//   Gl[r*STR+c], c==r : left-acc  for diagonal child (r,r)
//   Gl[r*STR+c], c< r : right-acc for child (c,r), transp. [unique writer/phase]
//   DR[r]             : right-acc for diagonal child (r,r)
extern "C" __global__ __launch_bounds__(NT, 1) void cky_kernel(
    const float* __restrict__ scores,
    const int* __restrict__ seq_lens,
    float* __restrict__ Z_out,
    float* __restrict__ marg_out)
{
    extern __shared__ float smem[];
    float* Al = smem;
    float* Gl = smem + LL * STR;
    float* DR = smem + 2 * LL * STR;

    const int b   = blockIdx.x;
    const int tid = threadIdx.x;
    const float* s = scores + (size_t)b * LL * LL;
    float* marg = marg_out + (size_t)b * LL * LL;
    const int len = seq_lens[b];

    for (int idx = tid; idx < LL * STR; idx += NT) Gl[idx] = 0.0f;
    if (tid < LL) DR[tid] = 0.0f;
    if (tid < len) Al[tid * STR + tid] = softplus_f(s[tid * LL + tid]);
    lds_barrier();

    // ---------------- Inside pass (single-pass LSE, shift M = A[i][j-1]) ----
    // M = A[i][j-1] bounds max_k v_k from below via k=j-1, so sum >= exp(A[j][j])
    // >= 1 (no log(0)); spread above M is O(10) for N(0,1) scores -> no overflow.
    for (int w = 1; w < len; ++w) {
        const int cells = len - w;
        const int clc = (cells > 1) ? (32 - __clz(cells - 1)) : 0;
        int gsh = 9 - clc; if (gsh > 4) gsh = 4;        // cells * g <= 512, g in {4,8,16}
        const int g    = 1 << gsh;
        const int gid  = tid >> gsh;
        const int lane = tid & (g - 1);
        if (gid < cells) {
            const int i = gid, j = gid + w;
            const float sv = s[i * LL + j];             // issued early; no drain at barrier
            const float M  = Al[i * STR + (j - 1)];
            const float* Arow = Al + i * STR1;          // A[i][i+e] at [e]
            const float* Acol = Al + (i + 1) * STR + j; // A[i+1+e][j] at [e*STR]
            float acc = 0.0f;
            const int m2 = 2 * lane;
            #pragma unroll 4
            for (int t = 0; 2 * g * t < w; ++t) {       // <= 4 trips by g sizing
                const int e = m2 + 2 * g * t;
                float2 a2 = *(const float2*)(Arow + e); // speculative; masked below
                float c0 = Acol[e * STR];
                float c1 = Acol[(e + 1) * STR];
                float e0 = __expf(a2.x + c0 - M);
                float e1 = __expf(a2.y + c1 - M);
                acc += (e     < w) ? e0 : 0.0f;         // garbage/NaN discarded by select
                acc += (e + 1 < w) ? e1 : 0.0f;
            }
            for (int off = g >> 1; off; off >>= 1)
                acc += __shfl_xor(acc, off, 64);        // <=4 hops, offsets <=8 (DPP)
            if (lane == 0) {
                const float Sij = M + __logf(acc);
                Al[j * STR + i] = Sij;                  // S^T
                Al[i * STR + j] = Sij + softplus_f(sv); // A
            }
        }
        lds_barrier();
    }

    if (tid == 0) Z_out[b] = Al[len - 1];               // A[0][len-1]

    // ---------------- Outside pass (race-free paired scatter) ---------------
    // Parent (i,J): t_e = exp(A[i,i+e] + A[i+e+1,J] - (S[i,J] - log G[i,J])) <= 1.
    //   left child (i,i+e)  -> Gl[i*STR+(i+e)]  (e=0 hits Gl's diag slot)
    //   right child (i+e+1,J) -> Gl[J*STR+(i+e+1)] (e=w-1 peeled to DR[J])
    for (int w = len - 1; w >= 1; --w) {
        const int cells = len - w;
        const int clc = (cells > 1) ? (32 - __clz(cells - 1)) : 0;
        int gsh = 9 - clc; if (gsh > 4) gsh = 4;
        const int g    = 1 << gsh;
        const int gid  = tid >> gsh;
        const int lane = tid & (g - 1);
        if (gid < cells) {
            const int i = gid, J = i + w;
            float Gp = Gl[i * STR + J] + Gl[J * STR + i];   // finalized at this phase
            if (i == 0 && J == len - 1) Gp += 1.0f;         // root seed
            if (Gp > 0.0f) {
                const float SL = Al[J * STR + i] - __logf(Gp);  // S[i,J] - log Gp (LDS)
                const float* Arow = Al + i * STR1;
                const float* Acol = Al + (i + 1) * STR + J;
                float*       Lrow = Gl + i * STR1;          // left-acc row (e=0 = diag slot)
                float*       Rrow = Gl + J * STR + i + 1;   // right-acc row J (transposed)
                const int bulk = w - 1;                     // e in [0,w-1); e=w-1 peeled
                const int m2 = 2 * lane;
                #pragma unroll 4
                for (int t = 0; (t + 1) * 2 * g <= bulk; ++t) {  // wave-uniform FULL trips
                    const int e = m2 + 2 * g * t;
                    float2 a2 = *(const float2*)(Arow + e);
                    float t0 = __expf(a2.x + Acol[e * STR]       - SL);
                    float t1 = __expf(a2.y + Acol[(e + 1) * STR] - SL);
                    float2 l2 = *(const float2*)(Lrow + e);
                    l2.x += t0; l2.y += t1;
                    *(float2*)(Lrow + e) = l2;
                    float r0 = Rrow[e] + t0;
                    float r1 = Rrow[e + 1] + t1;
                    Rrow[e] = r0; Rrow[e + 1] = r1;
                }
                const int e0 = (bulk / (2 * g)) * (2 * g);  // remainder edges
                for (int e = e0 + lane; e < bulk; e += g) {
                    float tt = __expf(Arow[e] + Acol[e * STR] - SL);
                    Lrow[e] += tt;
                    Rrow[e] += tt;
                }
                if (lane == 0) {                            // final edge e = w-1
                    float tt = __expf(Arow[w - 1] + Al[J * STR + J] - SL);
                    Lrow[w - 1] += tt;
                    DR[J]       += tt;
                }
            }
        }
        lds_barrier();
    }

    // ---------------- Epilogue: marg + Z, coalesced ----------------
    for (int idx = tid; idx < LL * LL; idx += NT) {
        const int r = idx >> 7, c = idx & (LL - 1);
        float G = 0.0f;
        if (c < len) {
            if (c > r)       G = Gl[r * STR + c] + Gl[c * STR + r];
            else if (c == r) G = Gl[r * STR + r] + DR[r];
            if (r == 0 && c == len - 1) G += 1.0f;          // root
        }
        float m = 0.0f;
        if (G != 0.0f) {
            const float sv = s[idx];
            m = G / (1.0f + __expf(-sv));                   // G * sigmoid(s)
        }
        marg[idx] = m;
    }
}

extern "C" void kernel_launch(void* const* d_in, const int* in_sizes, int n_in,
                              void* d_out, int out_size, void* d_ws, size_t ws_size,
                              hipStream_t stream) {
    const float* scores  = (const float*)d_in[0];
    const int* seq_lens  = (const int*)d_in[1];
    const int B = in_sizes[1];              // 32
    float* out = (float*)d_out;
    float* Z_out = out;                     // B floats
    float* marg  = out + B;                 // B*L*L floats

    const size_t lds_bytes = (size_t)(2 * LL * STR + LL) * sizeof(float);  // 138752 B
    hipFuncSetAttribute((const void*)cky_kernel,
                        hipFuncAttributeMaxDynamicSharedMemorySize,
                        (int)lds_bytes);
    cky_kernel<<<B, NT, lds_bytes, stream>>>(scores, seq_lens, Z_out, marg);
}